// Round 7
// baseline (815.560 us; speedup 1.0000x reference)
//
#include <hip/hip_runtime.h>

#define DEVINL __device__ __forceinline__

typedef __attribute__((ext_vector_type(4))) float f32x4;

static constexpr int SS = 12288;   // S = NKV
static constexpr float QKS = 0.17677669529663687f;  // 1/sqrt(32)

DEVINL f32x4 f32x4_zero() { f32x4 z; z[0]=0.f; z[1]=0.f; z[2]=0.f; z[3]=0.f; return z; }

DEVINL f32x4 mfma8(long long a, long long b, f32x4 c) {
  return __builtin_amdgcn_mfma_f32_16x16x32_fp8_fp8(a, b, c, 0, 0, 0);
}

// pack 4 floats -> 4 fp8 e4m3 bytes
DEVINL unsigned pk4_fp8(float a, float b, float c, float d) {
#if __has_builtin(__builtin_amdgcn_cvt_pk_fp8_f32)
  int r = 0;
  r = __builtin_amdgcn_cvt_pk_fp8_f32(a, b, r, false);
  r = __builtin_amdgcn_cvt_pk_fp8_f32(c, d, r, true);
  return (unsigned)r;
#else
  unsigned r;
  asm("v_cvt_pk_fp8_f32 %0, %1, %2" : "=v"(r) : "v"(a), "v"(b));
  asm("v_cvt_pk_fp8_f32 %0, %1, %2 op_sel:[0,0,1]" : "+v"(r) : "v"(c), "v"(d));
  return r;
#endif
}
DEVINL unsigned char f2fp8(float x) { return (unsigned char)(pk4_fp8(x, x, x, x) & 0xFF); }

// fp8 e4m3fn byte -> float
DEVINL float fp8_to_f32(unsigned b) {
  unsigned e = (b >> 3) & 15, m = b & 7;
  float v;
  if (e == 0) v = (float)m * 0.001953125f;                                  // m * 2^-9
  else v = __builtin_bit_cast(float, ((e + 120u) << 23) | (m << 20));
  return (b & 0x80u) ? -v : v;
}
DEVINL void unpk4_fp8(unsigned w, float* o) {
#if __has_builtin(__builtin_amdgcn_cvt_f32_fp8)
  o[0] = __builtin_amdgcn_cvt_f32_fp8((int)w, 0);
  o[1] = __builtin_amdgcn_cvt_f32_fp8((int)w, 1);
  o[2] = __builtin_amdgcn_cvt_f32_fp8((int)w, 2);
  o[3] = __builtin_amdgcn_cvt_f32_fp8((int)w, 3);
#else
  o[0] = fp8_to_f32(w & 0xFF); o[1] = fp8_to_f32((w >> 8) & 0xFF);
  o[2] = fp8_to_f32((w >> 16) & 0xFF); o[3] = fp8_to_f32(w >> 24);
#endif
}

// swizzled byte offset into a [16 q][128 c] fp8 LDS tile: 8B-chunk ^= q
DEVINL int xoff(int q, int c) {
  return q * 128 + ((((c >> 3) ^ q) & 15) << 3) + (c & 7);
}
DEVINL void wave_sync() {
  asm volatile("s_waitcnt lgkmcnt(0)" ::: "memory");
  __builtin_amdgcn_sched_barrier(0);
}
DEVINL float gelu_f(float x) {
  float u = 0.7978845608028654f * (x + 0.044715f * x * x * x);
  float t = 1.0f - 2.0f / (__expf(2.0f * u) + 1.0f);
  return 0.5f * x * (1.0f + t);
}

// stage one full 16 KB fp8 weight matrix -> LDS slot (4 x gload_lds16 / thread)
DEVINL void stage16(const unsigned char* __restrict__ src, unsigned char* slot, int tid) {
  const int wv = tid >> 6, l = tid & 63;
#pragma unroll
  for (int r = 0; r < 4; ++r) {
    int off = (r * 4 + wv) * 1024;
    __builtin_amdgcn_global_load_lds(
        (const __attribute__((address_space(1))) unsigned int*)(src + off + l * 16),
        (__attribute__((address_space(3))) unsigned int*)(slot + off), 16, 0, 0);
  }
}

// ---------------------------------------------------------------------------
// Kernel 0: repack six 128x128 fp32 weights into fp8 MFMA A-frag order (A=W^T)
// addr = mat*16384 + half*8192 + (mt*64+l)*16 + ktl*8 + i, kt = half*2+ktl,
// holds W[kt*32+(l>>4)*8+i][mt*16+(l&15)].
// ---------------------------------------------------------------------------
__global__ void prep_weights(const float* __restrict__ w0, const float* __restrict__ w1,
                             const float* __restrict__ w2, const float* __restrict__ w3,
                             const float* __restrict__ w4, const float* __restrict__ w5,
                             unsigned char* __restrict__ wfrag) {
  int gid = blockIdx.x * 256 + threadIdx.x;   // < 98304
  int i   = gid & 7;
  int ktl = (gid >> 3) & 1;
  int l   = (gid >> 4) & 63;
  int mt  = (gid >> 10) & 7;
  int hf  = (gid >> 13) & 1;
  int mat = gid >> 14;
  const float* W = (mat == 0) ? w0 : (mat == 1) ? w1 : (mat == 2) ? w2
                 : (mat == 3) ? w3 : (mat == 4) ? w4 : w5;
  int kt = hf * 2 + ktl;
  int k = kt * 32 + (l >> 4) * 8 + i;
  int c = mt * 16 + (l & 15);
  wfrag[gid] = f2fp8(W[k * 128 + c]);
}

// ---------------------------------------------------------------------------
// Kernel 1: kv = LN(x_kv) @ Wkv + bkv -> fp8 workspace [24576][256]
// ---------------------------------------------------------------------------
__global__ __launch_bounds__(256) void kv_proj(
    const float* __restrict__ xkv, const float* __restrict__ lns,
    const float* __restrict__ lnb, const float* __restrict__ Wkv,
    const float* __restrict__ bkv, unsigned char* __restrict__ kvout) {
  __shared__ float y[16][132];
  const int tid = threadIdx.x;
  const size_t rb = (size_t)blockIdx.x * 16;
  {
    int r = tid >> 4, p = tid & 15;
    const float* xr = xkv + (rb + r) * 128 + p * 8;
    float v[8];
    float sum = 0.f, sq = 0.f;
#pragma unroll
    for (int i = 0; i < 2; ++i) {
      float4 q4 = *(const float4*)(xr + i * 4);
      v[i*4+0]=q4.x; v[i*4+1]=q4.y; v[i*4+2]=q4.z; v[i*4+3]=q4.w;
      sum += q4.x + q4.y + q4.z + q4.w;
      sq  += q4.x*q4.x + q4.y*q4.y + q4.z*q4.z + q4.w*q4.w;
    }
    sum += __shfl_xor(sum, 1, 16); sum += __shfl_xor(sum, 2, 16);
    sum += __shfl_xor(sum, 4, 16); sum += __shfl_xor(sum, 8, 16);
    sq  += __shfl_xor(sq, 1, 16);  sq  += __shfl_xor(sq, 2, 16);
    sq  += __shfl_xor(sq, 4, 16);  sq  += __shfl_xor(sq, 8, 16);
    float mu = sum * (1.0f/128.f);
    float rs = rsqrtf(sq * (1.0f/128.f) - mu*mu + 1e-5f);
#pragma unroll
    for (int i = 0; i < 8; ++i) {
      int c = p * 8 + i;
      y[r][c] = (v[i] - mu) * rs * lns[c] + lnb[c];
    }
  }
  __syncthreads();
  const int c2 = tid;
  float acc[16];
#pragma unroll
  for (int r = 0; r < 16; ++r) acc[r] = 0.f;
  for (int c = 0; c < 128; c += 4) {
    float w0 = Wkv[(c+0)*256 + c2];
    float w1 = Wkv[(c+1)*256 + c2];
    float w2 = Wkv[(c+2)*256 + c2];
    float w3 = Wkv[(c+3)*256 + c2];
#pragma unroll
    for (int r = 0; r < 16; ++r) {
      float4 yv = *(const float4*)&y[r][c];
      acc[r] += yv.x*w0 + yv.y*w1 + yv.z*w2 + yv.w*w3;
    }
  }
  float bb = bkv[c2];
#pragma unroll
  for (int r = 0; r < 16; ++r)
    kvout[(rb + r) * 256 + c2] = f2fp8(acc[r] + bb);
}

// ---------------------------------------------------------------------------
// mmF: per-wave flipped 16x128 @ 128x128 (A = W^T fp8 LDS, B = act fp8 X).
// Lane (lo,g) outputs channels c = mt*16+g*4..+3 of row q=lo. Inline per-mt
// epilogue, single f32x4 acc (no spills).
// MODE 0: +bias -> X.  MODE 1: +bias, gelu -> X.  MODE 4: *QKS -> X.
// ---------------------------------------------------------------------------
template <int MODE>
DEVINL void mmF(unsigned char* X, const unsigned char* W8,
                const float* __restrict__ bias, int lo, int g, int l) {
  long long bfr[4];
#pragma unroll
  for (int kt = 0; kt < 4; ++kt)
    bfr[kt] = *(const long long*)(X + xoff(lo, kt * 32 + g * 8));
#pragma unroll
  for (int mt = 0; mt < 8; ++mt) {
    ulonglong2 a01 = *(const ulonglong2*)(W8 + (mt * 64 + l) * 16);
    ulonglong2 a23 = *(const ulonglong2*)(W8 + 8192 + (mt * 64 + l) * 16);
    f32x4 a = f32x4_zero();
    a = mfma8((long long)a01.x, bfr[0], a);
    a = mfma8((long long)a01.y, bfr[1], a);
    a = mfma8((long long)a23.x, bfr[2], a);
    a = mfma8((long long)a23.y, bfr[3], a);
    int c0 = mt * 16 + g * 4;
    float v0 = a[0], v1 = a[1], v2 = a[2], v3 = a[3];
    if (MODE == 4) { v0 *= QKS; v1 *= QKS; v2 *= QKS; v3 *= QKS; }
    else {
      float4 b4 = *(const float4*)(bias + c0);
      v0 += b4.x; v1 += b4.y; v2 += b4.z; v3 += b4.w;
    }
    if (MODE == 1) { v0 = gelu_f(v0); v1 = gelu_f(v1); v2 = gelu_f(v2); v3 = gelu_f(v3); }
    *(unsigned*)(X + xoff(lo, c0)) = pk4_fp8(v0, v1, v2, v3);
  }
}

// o = ao @ W_out + b_out -> O (fp8)
DEVINL void mmF_o(unsigned char* X, const unsigned char* W8,
                  const float* __restrict__ bias, unsigned char* O,
                  int lo, int g, int l) {
  long long bfr[4];
#pragma unroll
  for (int kt = 0; kt < 4; ++kt)
    bfr[kt] = *(const long long*)(X + xoff(lo, kt * 32 + g * 8));
#pragma unroll
  for (int mt = 0; mt < 8; ++mt) {
    ulonglong2 a01 = *(const ulonglong2*)(W8 + (mt * 64 + l) * 16);
    ulonglong2 a23 = *(const ulonglong2*)(W8 + 8192 + (mt * 64 + l) * 16);
    f32x4 a = f32x4_zero();
    a = mfma8((long long)a01.x, bfr[0], a);
    a = mfma8((long long)a01.y, bfr[1], a);
    a = mfma8((long long)a23.x, bfr[2], a);
    a = mfma8((long long)a23.y, bfr[3], a);
    int c0 = mt * 16 + g * 4;
    float4 b4 = *(const float4*)(bias + c0);
    *(unsigned*)(O + xoff(lo, c0)) =
        pk4_fp8(a[0] + b4.x, a[1] + b4.y, a[2] + b4.z, a[3] + b4.w);
  }
}

// m = g1 @ W2 + b2; out = xq + gamma*o + gmlp*m -> global float4
DEVINL void mmF_out(unsigned char* X, const unsigned char* W8,
                    const float* __restrict__ bias, const float* __restrict__ gmv,
                    const float* __restrict__ gpv, const unsigned char* O,
                    const float* __restrict__ xqw, float* __restrict__ outw,
                    int lo, int g, int l) {
  float4 xr4[8];
#pragma unroll
  for (int mt = 0; mt < 8; ++mt)
    xr4[mt] = *(const float4*)(xqw + lo * 128 + mt * 16 + g * 4);
  long long bfr[4];
#pragma unroll
  for (int kt = 0; kt < 4; ++kt)
    bfr[kt] = *(const long long*)(X + xoff(lo, kt * 32 + g * 8));
#pragma unroll
  for (int mt = 0; mt < 8; ++mt) {
    ulonglong2 a01 = *(const ulonglong2*)(W8 + (mt * 64 + l) * 16);
    ulonglong2 a23 = *(const ulonglong2*)(W8 + 8192 + (mt * 64 + l) * 16);
    f32x4 a = f32x4_zero();
    a = mfma8((long long)a01.x, bfr[0], a);
    a = mfma8((long long)a01.y, bfr[1], a);
    a = mfma8((long long)a23.x, bfr[2], a);
    a = mfma8((long long)a23.y, bfr[3], a);
    int c0 = mt * 16 + g * 4;
    float4 b4 = *(const float4*)(bias + c0);
    float4 g4 = *(const float4*)(gmv + c0);
    float4 p4 = *(const float4*)(gpv + c0);
    float ov[4];
    unpk4_fp8(*(const unsigned*)(O + xoff(lo, c0)), ov);
    float4 o4;
    o4.x = xr4[mt].x + g4.x * ov[0] + p4.x * (a[0] + b4.x);
    o4.y = xr4[mt].y + g4.y * ov[1] + p4.y * (a[1] + b4.y);
    o4.z = xr4[mt].z + g4.z * ov[2] + p4.z * (a[2] + b4.z);
    o4.w = xr4[mt].w + g4.w * ov[3] + p4.w * (a[3] + b4.w);
    *(float4*)(outw + lo * 128 + c0) = o4;
  }
}

// ---------------------------------------------------------------------------
// Kernel 2: fused main. Block = 4 waves x (2 its) s-units; fp8 weight ping-pong
// (16 KB slots), 6 barriers/it; wave-local attention; o kept fp8 in LDS.
// ---------------------------------------------------------------------------
__global__ __launch_bounds__(256, 3) void fused_main(
    const float* __restrict__ xq, const int* __restrict__ nh_idx,
    const unsigned char* __restrict__ nh_mask,
    const unsigned char* __restrict__ wfrag,
    const unsigned char* __restrict__ kvws,
    const float* __restrict__ ln_q_s, const float* __restrict__ ln_q_b,
    const float* __restrict__ bq, const float* __restrict__ b_out,
    const float* __restrict__ gamma, const float* __restrict__ ln_m_s,
    const float* __restrict__ ln_m_b, const float* __restrict__ bm,
    const float* __restrict__ b1, const float* __restrict__ b2,
    const float* __restrict__ gmlp, float* __restrict__ out) {
  __shared__ __align__(16) unsigned char Wb[2][16384];
  __shared__ __align__(16) unsigned char SUb[4][5248];

  const int tid = threadIdx.x, l = tid & 63, wv = tid >> 6;
  const int lo = l & 15, g = l >> 4;
  unsigned char* X  = SUb[wv];          // 2048: act [16 q][128 c] swz / V^T overlay
  unsigned char* KP = SUb[wv] + 2048;   // 1152: K rows / P overlay
  unsigned char* O  = SUb[wv] + 3200;   // 2048: o (fp8)

  stage16(wfrag, Wb[0], tid);
  asm volatile("s_waitcnt vmcnt(0)" ::: "memory");
  __syncthreads();

  for (int it = 0; it < 2; ++it) {
    const int su = blockIdx.x * 8 + it * 4 + wv;   // < 24576
    const int t = su / SS, s = su - t * SS;
    const float* xqw = xq + (size_t)su * 2048;
    float* outw = out + (size_t)su * 2048;

    // ---- kv gather + nh meta
    uint4 kvr[3];
#pragma unroll
    for (int j = 0; j < 3; ++j) {
      int idx = j * 64 + l;
      if (idx < 144) {
        int jrow = nh_idx[s * 9 + (idx >> 4)];
        kvr[j] = *(const uint4*)(kvws + ((size_t)(t * SS + jrow)) * 256 + (idx & 15) * 16);
      }
    }
    float sbias[4];
#pragma unroll
    for (int e = 0; e < 4; ++e) {
      int n = g * 4 + e;
      sbias[e] = (n < 9) ? (nh_mask[s * 9 + n] ? 0.0f : -1e9f) : -1e9f;
    }

    // ---- LN1 -> X (fp8)
    {
      float4 xv[8];
      float sum = 0.f, sq = 0.f;
#pragma unroll
      for (int mt = 0; mt < 8; ++mt) {
        xv[mt] = *(const float4*)(xqw + lo * 128 + mt * 16 + g * 4);
        sum += xv[mt].x + xv[mt].y + xv[mt].z + xv[mt].w;
        sq  += xv[mt].x*xv[mt].x + xv[mt].y*xv[mt].y + xv[mt].z*xv[mt].z + xv[mt].w*xv[mt].w;
      }
      sum += __shfl_xor(sum, 16); sum += __shfl_xor(sum, 32);
      sq  += __shfl_xor(sq, 16);  sq  += __shfl_xor(sq, 32);
      float mu = sum * (1.0f/128.f);
      float rs = rsqrtf(sq * (1.0f/128.f) - mu*mu + 1e-5f);
#pragma unroll
      for (int mt = 0; mt < 8; ++mt) {
        int c0 = mt * 16 + g * 4;
        float4 s4 = *(const float4*)(ln_q_s + c0);
        float4 b4 = *(const float4*)(ln_q_b + c0);
        *(unsigned*)(X + xoff(lo, c0)) = pk4_fp8(
            (xv[mt].x - mu) * rs * s4.x + b4.x,
            (xv[mt].y - mu) * rs * s4.y + b4.y,
            (xv[mt].z - mu) * rs * s4.z + b4.z,
            (xv[mt].w - mu) * rs * s4.w + b4.w);
      }
    }
    // ---- land K rows (fp8, even-mask chunk swizzle keeps 16B writes intact)
#pragma unroll
    for (int j = 0; j < 3; ++j) {
      int idx = j * 64 + l;
      if (idx < 144 && (idx & 15) < 8) {
        int n = idx >> 4, ch = idx & 15;
        *(uint4*)(KP + n * 128 + (((ch * 2) ^ (n & 14)) << 3)) = kvr[j];
      }
    }
    wave_sync();

    // m0: q = y1 @ Wq + bq          (slot0; stage m1->slot1)
    stage16(wfrag + 1 * 16384, Wb[1], tid);
    mmF<0>(X, Wb[0], bq, lo, g, l);
    __syncthreads();
    // m1: qh = (q @ Wa_q) * QKS     (slot1; stage m2->slot0)
    stage16(wfrag + 2 * 16384, Wb[0], tid);
    mmF<4>(X, Wb[1], nullptr, lo, g, l);
    __syncthreads();

    // ---- attention (wave-local, all-MFMA)
    {
      int nc = lo > 8 ? 8 : lo;   // K-row clamp; garbage rows killed by sbias
      long long ka[4], qb[4];
#pragma unroll
      for (int h = 0; h < 4; ++h) {
        ka[h] = *(const long long*)(KP + nc * 128 + ((((h * 4 + g) ^ (nc & 14))) << 3));
        qb[h] = *(const long long*)(X + xoff(lo, h * 32 + g * 8));
      }
      f32x4 st[4];
#pragma unroll
      for (int h = 0; h < 4; ++h) st[h] = mfma8(ka[h], qb[h], f32x4_zero());
      wave_sync();   // K/qh reads retired -> KP/X reusable
#pragma unroll
      for (int h = 0; h < 4; ++h) {
        float p0 = st[h][0] + sbias[0], p1 = st[h][1] + sbias[1];
        float p2 = st[h][2] + sbias[2], p3 = st[h][3] + sbias[3];
        float m = fmaxf(fmaxf(p0, p1), fmaxf(p2, p3));
        m = fmaxf(m, __shfl_xor(m, 16)); m = fmaxf(m, __shfl_xor(m, 32));
        p0 = __expf(p0 - m); p1 = __expf(p1 - m);
        p2 = __expf(p2 - m); p3 = __expf(p3 - m);
        float ss = p0 + p1 + p2 + p3;
        ss += __shfl_xor(ss, 16); ss += __shfl_xor(ss, 32);
        float inv = 1.0f / ss;
        *(unsigned*)(KP + h * 256 + lo * 16 + g * 4) =
            pk4_fp8(p0 * inv, p1 * inv, p2 * inv, p3 * inv);   // P[h][q][n]
      }
      {  // zero V^T region (X), then land V^T[d][16 n]
        uint4 z; z.x = 0u; z.y = 0u; z.z = 0u; z.w = 0u;
        *(uint4*)(X + l * 32) = z;
        *(uint4*)(X + l * 32 + 16) = z;
      }
      wave_sync();
#pragma unroll
      for (int j = 0; j < 3; ++j) {
        int idx = j * 64 + l;
        if (idx < 144 && (idx & 15) >= 8) {
          int n = idx >> 4, d0 = ((idx & 15) - 8) * 16;
          unsigned w0 = kvr[j].x, w1 = kvr[j].y, w2 = kvr[j].z, w3 = kvr[j].w;
#pragma unroll
          for (int dd = 0; dd < 16; ++dd) {
            unsigned wsel = (dd < 4) ? w0 : (dd < 8) ? w1 : (dd < 12) ? w2 : w3;
            X[(d0 + dd) * 16 + n] = (unsigned char)((wsel >> ((dd & 3) * 8)) & 0xFF);
          }
        }
      }
      wave_sync();
      long long pbh[4];
#pragma unroll
      for (int h = 0; h < 4; ++h)
        pbh[h] = (g < 2) ? *(const long long*)(KP + h * 256 + lo * 16 + g * 8) : 0LL;
      f32x4 oacc[8];
#pragma unroll
      for (int mt = 0; mt < 8; ++mt) {
        long long va = (g < 2) ? *(const long long*)(X + (mt * 16 + lo) * 16 + g * 8) : 0LL;
        oacc[mt] = mfma8(va, pbh[mt >> 1], f32x4_zero());
      }
      wave_sync();   // V^T reads done -> overwrite X with ao
#pragma unroll
      for (int mt = 0; mt < 8; ++mt)
        *(unsigned*)(X + xoff(lo, mt * 16 + g * 4)) =
            pk4_fp8(oacc[mt][0], oacc[mt][1], oacc[mt][2], oacc[mt][3]);
      wave_sync();
    }

    // m2: o = ao @ W_out + b_out -> O (slot0; stage m3->slot1)
    stage16(wfrag + 3 * 16384, Wb[1], tid);
    mmF_o(X, Wb[0], b_out, O, lo, g, l);
    __syncthreads();

    // ---- LN2: x2 = xq + gamma*o (recomputed), y2 -> X (fp8)
    {
      float4 xr4[8];
      unsigned ow[8];
      float sum = 0.f, sq = 0.f;
#pragma unroll
      for (int mt = 0; mt < 8; ++mt) {
        int c0 = mt * 16 + g * 4;
        xr4[mt] = *(const float4*)(xqw + lo * 128 + c0);
        ow[mt] = *(const unsigned*)(O + xoff(lo, c0));
        float ov[4];
        unpk4_fp8(ow[mt], ov);
        float4 g4 = *(const float4*)(gamma + c0);
        float a = xr4[mt].x + g4.x * ov[0];
        float b = xr4[mt].y + g4.y * ov[1];
        float c = xr4[mt].z + g4.z * ov[2];
        float d = xr4[mt].w + g4.w * ov[3];
        sum += a + b + c + d;
        sq  += a*a + b*b + c*c + d*d;
      }
      sum += __shfl_xor(sum, 16); sum += __shfl_xor(sum, 32);
      sq  += __shfl_xor(sq, 16);  sq  += __shfl_xor(sq, 32);
      float mu = sum * (1.0f/128.f);
      float rs = rsqrtf(sq * (1.0f/128.f) - mu*mu + 1e-5f);
#pragma unroll
      for (int mt = 0; mt < 8; ++mt) {
        int c0 = mt * 16 + g * 4;
        float ov[4];
        unpk4_fp8(ow[mt], ov);
        float4 g4 = *(const float4*)(gamma + c0);
        float4 s4 = *(const float4*)(ln_m_s + c0);
        float4 b4 = *(const float4*)(ln_m_b + c0);
        *(unsigned*)(X + xoff(lo, c0)) = pk4_fp8(
            ((xr4[mt].x + g4.x * ov[0]) - mu) * rs * s4.x + b4.x,
            ((xr4[mt].y + g4.y * ov[1]) - mu) * rs * s4.y + b4.y,
            ((xr4[mt].z + g4.z * ov[2]) - mu) * rs * s4.z + b4.z,
            ((xr4[mt].w + g4.w * ov[3]) - mu) * rs * s4.w + b4.w);
      }
    }
    wave_sync();

    // m3: h1 = y2 @ Wm + bm        (slot1; stage m4->slot0)
    stage16(wfrag + 4 * 16384, Wb[0], tid);
    mmF<0>(X, Wb[1], bm, lo, g, l);
    __syncthreads();
    // m4: g1 = gelu(h1 @ W1 + b1)  (slot0; stage m5->slot1)
    stage16(wfrag + 5 * 16384, Wb[1], tid);
    mmF<1>(X, Wb[0], b1, lo, g, l);
    __syncthreads();
    // m5: m = g1 @ W2 + b2; out = xq + gamma*o + gmlp*m  (slot1; stage m0 next it)
    if (it == 0) stage16(wfrag, Wb[0], tid);
    mmF_out(X, Wb[1], b2, gamma, gmlp, O, xqw, outw, lo, g, l);
    __syncthreads();
  }
}

// ---------------------------------------------------------------------------
extern "C" void kernel_launch(void* const* d_in, const int* in_sizes, int n_in,
                              void* d_out, int out_size, void* d_ws, size_t ws_size,
                              hipStream_t stream) {
  const float* x_q     = (const float*)d_in[0];
  const float* x_kv    = (const float*)d_in[1];
  const int* nh_idx    = (const int*)d_in[2];
  const unsigned char* nh_mask = (const unsigned char*)d_in[3];
  const float* ln_q_s  = (const float*)d_in[4];
  const float* ln_q_b  = (const float*)d_in[5];
  const float* Wq      = (const float*)d_in[6];
  const float* bq      = (const float*)d_in[7];
  const float* ln_kv_s = (const float*)d_in[8];
  const float* ln_kv_b = (const float*)d_in[9];
  const float* Wkv     = (const float*)d_in[10];
  const float* bkv     = (const float*)d_in[11];
  const float* Wa_q    = (const float*)d_in[12];
  const float* W_out   = (const float*)d_in[13];
  const float* b_out   = (const float*)d_in[14];
  const float* gamma   = (const float*)d_in[15];
  const float* ln_m_s  = (const float*)d_in[16];
  const float* ln_m_b  = (const float*)d_in[17];
  const float* Wm      = (const float*)d_in[18];
  const float* bm      = (const float*)d_in[19];
  const float* W1      = (const float*)d_in[20];
  const float* b1      = (const float*)d_in[21];
  const float* W2      = (const float*)d_in[22];
  const float* b2      = (const float*)d_in[23];
  const float* gmlp    = (const float*)d_in[24];

  unsigned char* wfrag = (unsigned char*)d_ws;          // 98304 B fp8 weight frags
  unsigned char* kvws  = wfrag + 98304;                 // 24576*256 fp8 kv

  prep_weights<<<384, 256, 0, stream>>>(Wq, Wa_q, W_out, Wm, W1, W2, wfrag);
  kv_proj<<<1536, 256, 0, stream>>>(x_kv, ln_kv_s, ln_kv_b, Wkv, bkv, kvws);
  fused_main<<<3072, 256, 0, stream>>>(
      x_q, nh_idx, nh_mask, wfrag, kvws, ln_q_s, ln_q_b, bq, b_out, gamma,
      ln_m_s, ln_m_b, bm, b1, b2, gmlp, (float*)d_out);
}

// Round 8
// 724.763 us; speedup vs baseline: 1.1253x; 1.1253x over previous
//
#include <hip/hip_runtime.h>

#define DEVINL __device__ __forceinline__

typedef __attribute__((ext_vector_type(4))) float f32x4;

static constexpr int SS = 12288;   // S = NKV
static constexpr float QKS = 0.17677669529663687f;  // 1/sqrt(32)

DEVINL f32x4 f32x4_zero() { f32x4 z; z[0]=0.f; z[1]=0.f; z[2]=0.f; z[3]=0.f; return z; }

DEVINL f32x4 mfma8(long long a, long long b, f32x4 c) {
  return __builtin_amdgcn_mfma_f32_16x16x32_fp8_fp8(a, b, c, 0, 0, 0);
}

// pack 4 floats -> 4 fp8 e4m3 bytes
DEVINL unsigned pk4_fp8(float a, float b, float c, float d) {
#if __has_builtin(__builtin_amdgcn_cvt_pk_fp8_f32)
  int r = 0;
  r = __builtin_amdgcn_cvt_pk_fp8_f32(a, b, r, false);
  r = __builtin_amdgcn_cvt_pk_fp8_f32(c, d, r, true);
  return (unsigned)r;
#else
  unsigned r;
  asm("v_cvt_pk_fp8_f32 %0, %1, %2" : "=v"(r) : "v"(a), "v"(b));
  asm("v_cvt_pk_fp8_f32 %0, %1, %2 op_sel:[0,0,1]" : "+v"(r) : "v"(c), "v"(d));
  return r;
#endif
}
DEVINL unsigned char f2fp8(float x) { return (unsigned char)(pk4_fp8(x, x, x, x) & 0xFF); }

// fp8 e4m3fn byte -> float (fallback)
DEVINL float fp8_to_f32(unsigned b) {
  unsigned e = (b >> 3) & 15, m = b & 7;
  float v;
  if (e == 0) v = (float)m * 0.001953125f;
  else v = __builtin_bit_cast(float, ((e + 120u) << 23) | (m << 20));
  return (b & 0x80u) ? -v : v;
}
DEVINL void unpk4_fp8(unsigned w, float* o) {
#if __has_builtin(__builtin_amdgcn_cvt_f32_fp8)
  o[0] = __builtin_amdgcn_cvt_f32_fp8((int)w, 0);
  o[1] = __builtin_amdgcn_cvt_f32_fp8((int)w, 1);
  o[2] = __builtin_amdgcn_cvt_f32_fp8((int)w, 2);
  o[3] = __builtin_amdgcn_cvt_f32_fp8((int)w, 3);
#else
  o[0] = fp8_to_f32(w & 0xFF); o[1] = fp8_to_f32((w >> 8) & 0xFF);
  o[2] = fp8_to_f32((w >> 16) & 0xFF); o[3] = fp8_to_f32(w >> 24);
#endif
}

// swizzled byte offset into a [16 q][128 c] fp8 LDS tile: 8B-chunk ^= q
DEVINL int xoff(int q, int c) {
  return q * 128 + ((((c >> 3) ^ q) & 15) << 3) + (c & 7);
}
DEVINL void wave_sync() {
  asm volatile("s_waitcnt lgkmcnt(0)" ::: "memory");
  __builtin_amdgcn_sched_barrier(0);
}
DEVINL float gelu_f(float x) {
  float u = 0.7978845608028654f * (x + 0.044715f * x * x * x);
  float t = 1.0f - 2.0f / (__expf(2.0f * u) + 1.0f);
  return 0.5f * x * (1.0f + t);
}

// stage one full 16 KB fp8 weight matrix -> LDS slot
DEVINL void stage16(const unsigned char* __restrict__ src, unsigned char* slot, int tid) {
  const int wv = tid >> 6, l = tid & 63;
#pragma unroll
  for (int r = 0; r < 4; ++r) {
    int off = (r * 4 + wv) * 1024;
    __builtin_amdgcn_global_load_lds(
        (const __attribute__((address_space(1))) unsigned int*)(src + off + l * 16),
        (__attribute__((address_space(3))) unsigned int*)(slot + off), 16, 0, 0);
  }
}

// ---------------------------------------------------------------------------
// Kernel 0: repack six 128x128 fp32 weights into fp8 MFMA A-frag order (A=W^T)
// ---------------------------------------------------------------------------
__global__ void prep_weights(const float* __restrict__ w0, const float* __restrict__ w1,
                             const float* __restrict__ w2, const float* __restrict__ w3,
                             const float* __restrict__ w4, const float* __restrict__ w5,
                             unsigned char* __restrict__ wfrag) {
  int gid = blockIdx.x * 256 + threadIdx.x;   // < 98304
  int i   = gid & 7;
  int ktl = (gid >> 3) & 1;
  int l   = (gid >> 4) & 63;
  int mt  = (gid >> 10) & 7;
  int hf  = (gid >> 13) & 1;
  int mat = gid >> 14;
  const float* W = (mat == 0) ? w0 : (mat == 1) ? w1 : (mat == 2) ? w2
                 : (mat == 3) ? w3 : (mat == 4) ? w4 : w5;
  int kt = hf * 2 + ktl;
  int k = kt * 32 + (l >> 4) * 8 + i;
  int c = mt * 16 + (l & 15);
  wfrag[gid] = f2fp8(W[k * 128 + c]);
}

// ---------------------------------------------------------------------------
// Kernel 1: kv = LN(x_kv) @ Wkv + bkv -> fp8 workspace [24576][256]
// ---------------------------------------------------------------------------
__global__ __launch_bounds__(256) void kv_proj(
    const float* __restrict__ xkv, const float* __restrict__ lns,
    const float* __restrict__ lnb, const float* __restrict__ Wkv,
    const float* __restrict__ bkv, unsigned char* __restrict__ kvout) {
  __shared__ float y[16][132];
  const int tid = threadIdx.x;
  const size_t rb = (size_t)blockIdx.x * 16;
  {
    int r = tid >> 4, p = tid & 15;
    const float* xr = xkv + (rb + r) * 128 + p * 8;
    float v[8];
    float sum = 0.f, sq = 0.f;
#pragma unroll
    for (int i = 0; i < 2; ++i) {
      float4 q4 = *(const float4*)(xr + i * 4);
      v[i*4+0]=q4.x; v[i*4+1]=q4.y; v[i*4+2]=q4.z; v[i*4+3]=q4.w;
      sum += q4.x + q4.y + q4.z + q4.w;
      sq  += q4.x*q4.x + q4.y*q4.y + q4.z*q4.z + q4.w*q4.w;
    }
    sum += __shfl_xor(sum, 1, 16); sum += __shfl_xor(sum, 2, 16);
    sum += __shfl_xor(sum, 4, 16); sum += __shfl_xor(sum, 8, 16);
    sq  += __shfl_xor(sq, 1, 16);  sq  += __shfl_xor(sq, 2, 16);
    sq  += __shfl_xor(sq, 4, 16);  sq  += __shfl_xor(sq, 8, 16);
    float mu = sum * (1.0f/128.f);
    float rs = rsqrtf(sq * (1.0f/128.f) - mu*mu + 1e-5f);
#pragma unroll
    for (int i = 0; i < 8; ++i) {
      int c = p * 8 + i;
      y[r][c] = (v[i] - mu) * rs * lns[c] + lnb[c];
    }
  }
  __syncthreads();
  const int c2 = tid;
  float acc[16];
#pragma unroll
  for (int r = 0; r < 16; ++r) acc[r] = 0.f;
  for (int c = 0; c < 128; c += 4) {
    float w0 = Wkv[(c+0)*256 + c2];
    float w1 = Wkv[(c+1)*256 + c2];
    float w2 = Wkv[(c+2)*256 + c2];
    float w3 = Wkv[(c+3)*256 + c2];
#pragma unroll
    for (int r = 0; r < 16; ++r) {
      float4 yv = *(const float4*)&y[r][c];
      acc[r] += yv.x*w0 + yv.y*w1 + yv.z*w2 + yv.w*w3;
    }
  }
  float bb = bkv[c2];
#pragma unroll
  for (int r = 0; r < 16; ++r)
    kvout[(rb + r) * 256 + c2] = f2fp8(acc[r] + bb);
}

// ---------------------------------------------------------------------------
// mmF: per-wave flipped 16x128 @ 128x128 (A = W^T fp8 LDS, B = act fp8 X).
// MODE 0: +bias -> X.  MODE 1: +bias, gelu -> X.  MODE 4: *QKS -> X.
// ---------------------------------------------------------------------------
template <int MODE>
DEVINL void mmF(unsigned char* X, const unsigned char* W8,
                const float* __restrict__ bias, int lo, int g, int l) {
  long long bfr[4];
#pragma unroll
  for (int kt = 0; kt < 4; ++kt)
    bfr[kt] = *(const long long*)(X + xoff(lo, kt * 32 + g * 8));
#pragma unroll
  for (int mt = 0; mt < 8; ++mt) {
    ulonglong2 a01 = *(const ulonglong2*)(W8 + (mt * 64 + l) * 16);
    ulonglong2 a23 = *(const ulonglong2*)(W8 + 8192 + (mt * 64 + l) * 16);
    f32x4 a = f32x4_zero();
    a = mfma8((long long)a01.x, bfr[0], a);
    a = mfma8((long long)a01.y, bfr[1], a);
    a = mfma8((long long)a23.x, bfr[2], a);
    a = mfma8((long long)a23.y, bfr[3], a);
    int c0 = mt * 16 + g * 4;
    float v0 = a[0], v1 = a[1], v2 = a[2], v3 = a[3];
    if (MODE == 4) { v0 *= QKS; v1 *= QKS; v2 *= QKS; v3 *= QKS; }
    else {
      float4 b4 = *(const float4*)(bias + c0);
      v0 += b4.x; v1 += b4.y; v2 += b4.z; v3 += b4.w;
    }
    if (MODE == 1) { v0 = gelu_f(v0); v1 = gelu_f(v1); v2 = gelu_f(v2); v3 = gelu_f(v3); }
    *(unsigned*)(X + xoff(lo, c0)) = pk4_fp8(v0, v1, v2, v3);
  }
}

// o = ao @ W_out + b_out -> O (fp8)
DEVINL void mmF_o(unsigned char* X, const unsigned char* W8,
                  const float* __restrict__ bias, unsigned char* O,
                  int lo, int g, int l) {
  long long bfr[4];
#pragma unroll
  for (int kt = 0; kt < 4; ++kt)
    bfr[kt] = *(const long long*)(X + xoff(lo, kt * 32 + g * 8));
#pragma unroll
  for (int mt = 0; mt < 8; ++mt) {
    ulonglong2 a01 = *(const ulonglong2*)(W8 + (mt * 64 + l) * 16);
    ulonglong2 a23 = *(const ulonglong2*)(W8 + 8192 + (mt * 64 + l) * 16);
    f32x4 a = f32x4_zero();
    a = mfma8((long long)a01.x, bfr[0], a);
    a = mfma8((long long)a01.y, bfr[1], a);
    a = mfma8((long long)a23.x, bfr[2], a);
    a = mfma8((long long)a23.y, bfr[3], a);
    int c0 = mt * 16 + g * 4;
    float4 b4 = *(const float4*)(bias + c0);
    *(unsigned*)(O + xoff(lo, c0)) =
        pk4_fp8(a[0] + b4.x, a[1] + b4.y, a[2] + b4.z, a[3] + b4.w);
  }
}

// m = g1 @ W2 + b2; out = xq + gamma*o + gmlp*m (xq read inline, no arrays)
DEVINL void mmF_out(unsigned char* X, const unsigned char* W8,
                    const float* __restrict__ bias, const float* __restrict__ gmv,
                    const float* __restrict__ gpv, const unsigned char* O,
                    const float* __restrict__ xqw, float* __restrict__ outw,
                    int lo, int g, int l) {
  long long bfr[4];
#pragma unroll
  for (int kt = 0; kt < 4; ++kt)
    bfr[kt] = *(const long long*)(X + xoff(lo, kt * 32 + g * 8));
#pragma unroll
  for (int mt = 0; mt < 8; ++mt) {
    ulonglong2 a01 = *(const ulonglong2*)(W8 + (mt * 64 + l) * 16);
    ulonglong2 a23 = *(const ulonglong2*)(W8 + 8192 + (mt * 64 + l) * 16);
    f32x4 a = f32x4_zero();
    a = mfma8((long long)a01.x, bfr[0], a);
    a = mfma8((long long)a01.y, bfr[1], a);
    a = mfma8((long long)a23.x, bfr[2], a);
    a = mfma8((long long)a23.y, bfr[3], a);
    int c0 = mt * 16 + g * 4;
    float4 x4 = *(const float4*)(xqw + lo * 128 + c0);   // L3-hot re-read
    float4 b4 = *(const float4*)(bias + c0);
    float4 g4 = *(const float4*)(gmv + c0);
    float4 p4 = *(const float4*)(gpv + c0);
    float ov[4];
    unpk4_fp8(*(const unsigned*)(O + xoff(lo, c0)), ov);
    float4 o4;
    o4.x = x4.x + g4.x * ov[0] + p4.x * (a[0] + b4.x);
    o4.y = x4.y + g4.y * ov[1] + p4.y * (a[1] + b4.y);
    o4.z = x4.z + g4.z * ov[2] + p4.z * (a[2] + b4.z);
    o4.w = x4.w + g4.w * ov[3] + p4.w * (a[3] + b4.w);
    *(float4*)(outw + lo * 128 + c0) = o4;
  }
}

// ---------------------------------------------------------------------------
// Kernel 2: fused main. Block = 4 waves x 2 its; fp8 weight ping-pong (16 KB),
// kv gather lands IMMEDIATELY (K->KP, V^T->O region) so no register arrays
// survive a phase boundary. LN2/final epilogue re-read xq (L3) + o (LDS).
// ---------------------------------------------------------------------------
__global__ __launch_bounds__(256, 2) void fused_main(
    const float* __restrict__ xq, const int* __restrict__ nh_idx,
    const unsigned char* __restrict__ nh_mask,
    const unsigned char* __restrict__ wfrag,
    const unsigned char* __restrict__ kvws,
    const float* __restrict__ ln_q_s, const float* __restrict__ ln_q_b,
    const float* __restrict__ bq, const float* __restrict__ b_out,
    const float* __restrict__ gamma, const float* __restrict__ ln_m_s,
    const float* __restrict__ ln_m_b, const float* __restrict__ bm,
    const float* __restrict__ b1, const float* __restrict__ b2,
    const float* __restrict__ gmlp, float* __restrict__ out) {
  __shared__ __align__(16) unsigned char Wb[2][16384];
  __shared__ __align__(16) unsigned char SUb[4][5248];

  const int tid = threadIdx.x, l = tid & 63, wv = tid >> 6;
  const int lo = l & 15, g = l >> 4;
  unsigned char* X  = SUb[wv];          // 2048: act [16 q][128 c] swz
  unsigned char* KP = SUb[wv] + 2048;   // 1152: K rows / P overlay
  unsigned char* O  = SUb[wv] + 3200;   // 2048: V^T first, then o (fp8)

  stage16(wfrag, Wb[0], tid);
  asm volatile("s_waitcnt vmcnt(0)" ::: "memory");
  __syncthreads();

  for (int it = 0; it < 2; ++it) {
    const int su = blockIdx.x * 8 + it * 4 + wv;   // < 24576
    const int t = su / SS, s = su - t * SS;
    const float* xqw = xq + (size_t)su * 2048;
    float* outw = out + (size_t)su * 2048;

    float sbias[4];
#pragma unroll
    for (int e = 0; e < 4; ++e) {
      int n = g * 4 + e;
      sbias[e] = (n < 9) ? (nh_mask[s * 9 + n] ? 0.0f : -1e9f) : -1e9f;
    }

    // ---- P0a: zero V^T region (in-order LDS guarantees visibility to P0b)
    {
      uint4 z; z.x = 0u; z.y = 0u; z.z = 0u; z.w = 0u;
      *(uint4*)(O + l * 32) = z;
      *(uint4*)(O + l * 32 + 16) = z;
    }
    // ---- P0b: kv gather, landed immediately. K rows fp8-swizzled; V -> V^T[d][16n]
#pragma unroll
    for (int j = 0; j < 3; ++j) {
      int idx = j * 64 + l;
      if (idx < 144) {
        int n = idx >> 4, ch = idx & 15;
        uint4 kv4 = *(const uint4*)(kvws + ((size_t)(t * SS + nh_idx[s * 9 + n])) * 256 + ch * 16);
        if (ch < 8) {
          *(uint4*)(KP + n * 128 + (((ch * 2) ^ (n & 14)) << 3)) = kv4;
        } else {
          int d0 = (ch - 8) * 16;
#pragma unroll
          for (int dd = 0; dd < 16; ++dd) {
            unsigned wsel = (dd < 4) ? kv4.x : (dd < 8) ? kv4.y : (dd < 12) ? kv4.z : kv4.w;
            O[(d0 + dd) * 16 + n] = (unsigned char)((wsel >> ((dd & 3) * 8)) & 0xFF);
          }
        }
      }
    }

    // ---- P1: LN1 -> X (fp8)
    {
      float4 xv[8];
      float sum = 0.f, sq = 0.f;
#pragma unroll
      for (int mt = 0; mt < 8; ++mt) {
        xv[mt] = *(const float4*)(xqw + lo * 128 + mt * 16 + g * 4);
        sum += xv[mt].x + xv[mt].y + xv[mt].z + xv[mt].w;
        sq  += xv[mt].x*xv[mt].x + xv[mt].y*xv[mt].y + xv[mt].z*xv[mt].z + xv[mt].w*xv[mt].w;
      }
      sum += __shfl_xor(sum, 16); sum += __shfl_xor(sum, 32);
      sq  += __shfl_xor(sq, 16);  sq  += __shfl_xor(sq, 32);
      float mu = sum * (1.0f/128.f);
      float rs = rsqrtf(sq * (1.0f/128.f) - mu*mu + 1e-5f);
#pragma unroll
      for (int mt = 0; mt < 8; ++mt) {
        int c0 = mt * 16 + g * 4;
        float4 s4 = *(const float4*)(ln_q_s + c0);
        float4 b4 = *(const float4*)(ln_q_b + c0);
        *(unsigned*)(X + xoff(lo, c0)) = pk4_fp8(
            (xv[mt].x - mu) * rs * s4.x + b4.x,
            (xv[mt].y - mu) * rs * s4.y + b4.y,
            (xv[mt].z - mu) * rs * s4.z + b4.z,
            (xv[mt].w - mu) * rs * s4.w + b4.w);
      }
    }
    wave_sync();

    // m0: q = y1 @ Wq + bq          (slot0; stage m1->slot1)
    stage16(wfrag + 1 * 16384, Wb[1], tid);
    mmF<0>(X, Wb[0], bq, lo, g, l);
    __syncthreads();
    // m1: qh = (q @ Wa_q) * QKS     (slot1; stage m2->slot0)
    stage16(wfrag + 2 * 16384, Wb[0], tid);
    mmF<4>(X, Wb[1], nullptr, lo, g, l);
    __syncthreads();

    // ---- attention (wave-local, all-MFMA; V^T already resident in O)
    {
      int nc = lo > 8 ? 8 : lo;   // K-row clamp; garbage rows killed by sbias
      long long ka[4], qb[4];
#pragma unroll
      for (int h = 0; h < 4; ++h) {
        ka[h] = *(const long long*)(KP + nc * 128 + ((((h * 4 + g) ^ (nc & 14))) << 3));
        qb[h] = *(const long long*)(X + xoff(lo, h * 32 + g * 8));
      }
      f32x4 st[4];
#pragma unroll
      for (int h = 0; h < 4; ++h) st[h] = mfma8(ka[h], qb[h], f32x4_zero());
      wave_sync();   // K/qh reads retired -> KP/X reusable
#pragma unroll
      for (int h = 0; h < 4; ++h) {
        float p0 = st[h][0] + sbias[0], p1 = st[h][1] + sbias[1];
        float p2 = st[h][2] + sbias[2], p3 = st[h][3] + sbias[3];
        float m = fmaxf(fmaxf(p0, p1), fmaxf(p2, p3));
        m = fmaxf(m, __shfl_xor(m, 16)); m = fmaxf(m, __shfl_xor(m, 32));
        p0 = __expf(p0 - m); p1 = __expf(p1 - m);
        p2 = __expf(p2 - m); p3 = __expf(p3 - m);
        float ss = p0 + p1 + p2 + p3;
        ss += __shfl_xor(ss, 16); ss += __shfl_xor(ss, 32);
        float inv = 1.0f / ss;
        *(unsigned*)(KP + h * 256 + lo * 16 + g * 4) =
            pk4_fp8(p0 * inv, p1 * inv, p2 * inv, p3 * inv);   // P[h][q][n]
      }
      wave_sync();
      long long pbh[4];
#pragma unroll
      for (int h = 0; h < 4; ++h)
        pbh[h] = (g < 2) ? *(const long long*)(KP + h * 256 + lo * 16 + g * 8) : 0LL;
      f32x4 oacc[8];
#pragma unroll
      for (int mt = 0; mt < 8; ++mt) {
        long long va = (g < 2) ? *(const long long*)(O + (mt * 16 + lo) * 16 + g * 8) : 0LL;
        oacc[mt] = mfma8(va, pbh[mt >> 1], f32x4_zero());
      }
      wave_sync();   // V^T/P reads done -> overwrite X with ao
#pragma unroll
      for (int mt = 0; mt < 8; ++mt)
        *(unsigned*)(X + xoff(lo, mt * 16 + g * 4)) =
            pk4_fp8(oacc[mt][0], oacc[mt][1], oacc[mt][2], oacc[mt][3]);
      wave_sync();
    }

    // m2: o = ao @ W_out + b_out -> O (V^T dead)  (slot0; stage m3->slot1)
    stage16(wfrag + 3 * 16384, Wb[1], tid);
    mmF_o(X, Wb[0], b_out, O, lo, g, l);
    __syncthreads();

    // ---- LN2: two-pass, no arrays. x2 = xq + gamma*o recomputed per pass.
    {
      float sum = 0.f, sq = 0.f;
#pragma unroll
      for (int mt = 0; mt < 8; ++mt) {
        int c0 = mt * 16 + g * 4;
        float4 x4 = *(const float4*)(xqw + lo * 128 + c0);
        float ov[4];
        unpk4_fp8(*(const unsigned*)(O + xoff(lo, c0)), ov);
        float4 g4 = *(const float4*)(gamma + c0);
        float a = x4.x + g4.x * ov[0];
        float b = x4.y + g4.y * ov[1];
        float c = x4.z + g4.z * ov[2];
        float d = x4.w + g4.w * ov[3];
        sum += a + b + c + d;
        sq  += a*a + b*b + c*c + d*d;
      }
      sum += __shfl_xor(sum, 16); sum += __shfl_xor(sum, 32);
      sq  += __shfl_xor(sq, 16);  sq  += __shfl_xor(sq, 32);
      float mu = sum * (1.0f/128.f);
      float rs = rsqrtf(sq * (1.0f/128.f) - mu*mu + 1e-5f);
#pragma unroll
      for (int mt = 0; mt < 8; ++mt) {
        int c0 = mt * 16 + g * 4;
        float4 x4 = *(const float4*)(xqw + lo * 128 + c0);
        float ov[4];
        unpk4_fp8(*(const unsigned*)(O + xoff(lo, c0)), ov);
        float4 g4 = *(const float4*)(gamma + c0);
        float4 s4 = *(const float4*)(ln_m_s + c0);
        float4 b4 = *(const float4*)(ln_m_b + c0);
        *(unsigned*)(X + xoff(lo, c0)) = pk4_fp8(
            ((x4.x + g4.x * ov[0]) - mu) * rs * s4.x + b4.x,
            ((x4.y + g4.y * ov[1]) - mu) * rs * s4.y + b4.y,
            ((x4.z + g4.z * ov[2]) - mu) * rs * s4.z + b4.z,
            ((x4.w + g4.w * ov[3]) - mu) * rs * s4.w + b4.w);
      }
    }
    wave_sync();

    // m3: h1 = y2 @ Wm + bm        (slot1; stage m4->slot0)
    stage16(wfrag + 4 * 16384, Wb[0], tid);
    mmF<0>(X, Wb[1], bm, lo, g, l);
    __syncthreads();
    // m4: g1 = gelu(h1 @ W1 + b1)  (slot0; stage m5->slot1)
    stage16(wfrag + 5 * 16384, Wb[1], tid);
    mmF<1>(X, Wb[0], b1, lo, g, l);
    __syncthreads();
    // m5: m = g1 @ W2 + b2; out = xq + gamma*o + gmlp*m  (slot1; re-stage m0)
    if (it == 0) stage16(wfrag, Wb[0], tid);
    mmF_out(X, Wb[1], b2, gamma, gmlp, O, xqw, outw, lo, g, l);
    __syncthreads();
  }
}

// ---------------------------------------------------------------------------
extern "C" void kernel_launch(void* const* d_in, const int* in_sizes, int n_in,
                              void* d_out, int out_size, void* d_ws, size_t ws_size,
                              hipStream_t stream) {
  const float* x_q     = (const float*)d_in[0];
  const float* x_kv    = (const float*)d_in[1];
  const int* nh_idx    = (const int*)d_in[2];
  const unsigned char* nh_mask = (const unsigned char*)d_in[3];
  const float* ln_q_s  = (const float*)d_in[4];
  const float* ln_q_b  = (const float*)d_in[5];
  const float* Wq      = (const float*)d_in[6];
  const float* bq      = (const float*)d_in[7];
  const float* ln_kv_s = (const float*)d_in[8];
  const float* ln_kv_b = (const float*)d_in[9];
  const float* Wkv     = (const float*)d_in[10];
  const float* bkv     = (const float*)d_in[11];
  const float* Wa_q    = (const float*)d_in[12];
  const float* W_out   = (const float*)d_in[13];
  const float* b_out   = (const float*)d_in[14];
  const float* gamma   = (const float*)d_in[15];
  const float* ln_m_s  = (const float*)d_in[16];
  const float* ln_m_b  = (const float*)d_in[17];
  const float* Wm      = (const float*)d_in[18];
  const float* bm      = (const float*)d_in[19];
  const float* W1      = (const float*)d_in[20];
  const float* b1      = (const float*)d_in[21];
  const float* W2      = (const float*)d_in[22];
  const float* b2      = (const float*)d_in[23];
  const float* gmlp    = (const float*)d_in[24];

  unsigned char* wfrag = (unsigned char*)d_ws;          // 98304 B fp8 weight frags
  unsigned char* kvws  = wfrag + 98304;                 // 24576*256 fp8 kv

  prep_weights<<<384, 256, 0, stream>>>(Wq, Wa_q, W_out, Wm, W1, W2, wfrag);
  kv_proj<<<1536, 256, 0, stream>>>(x_kv, ln_kv_s, ln_kv_b, Wkv, bkv, kvws);
  fused_main<<<3072, 256, 0, stream>>>(
      x_q, nh_idx, nh_mask, wfrag, kvws, ln_q_s, ln_q_b, bq, b_out, gamma,
      ln_m_s, ln_m_b, bm, b1, b2, gmlp, (float*)d_out);
}

// Round 9
// 345.337 us; speedup vs baseline: 2.3616x; 2.0987x over previous
//
#include <hip/hip_runtime.h>
#include <hip/hip_bf16.h>

#define DEVINL __device__ __forceinline__

typedef __attribute__((ext_vector_type(8))) short bf16x8;
typedef __attribute__((ext_vector_type(4))) float f32x4;

static constexpr int SS = 12288;   // S = NKV
static constexpr float QKS = 0.17677669529663687f;  // 1/sqrt(32), folded into Wa_q

DEVINL f32x4 f32x4_zero() { f32x4 z; z[0]=0.f; z[1]=0.f; z[2]=0.f; z[3]=0.f; return z; }
DEVINL f32x4 mfma16(bf16x8 a, bf16x8 b, f32x4 c) {
  return __builtin_amdgcn_mfma_f32_16x16x32_bf16(a, b, c, 0, 0, 0);
}
DEVINL unsigned short f2bf(float f) {   // prep kernel only
  __hip_bfloat16 h = __float2bfloat16(f);
  return __builtin_bit_cast(unsigned short, h);
}
DEVINL float bf2f(unsigned short u) {
  unsigned v = ((unsigned)u) << 16;
  return __builtin_bit_cast(float, v);
}
DEVINL unsigned cvt_pk_bf16(float lo_, float hi_) {  // [15:0]=lo_, [31:16]=hi_
  unsigned r;
  asm volatile("v_cvt_pk_bf16_f32 %0, %1, %2" : "=v"(r) : "v"(lo_), "v"(hi_));
  return r;
}
// 8-way XOR-swizzled element offset into a [16][128] bf16 LDS tile (R5-proven)
DEVINL int swz(int r, int c) {
  return (r << 7) + ((((c >> 3) ^ (r & 7))) << 3) + (c & 7);
}
DEVINL void wave_sync() {
  asm volatile("s_waitcnt lgkmcnt(0)" ::: "memory");
  __builtin_amdgcn_sched_barrier(0);
}
DEVINL float gelu_f(float x) {  // tanh-approximate gelu (jax default)
  float u = 0.7978845608028654f * (x + 0.044715f * x * x * x);
  float t = 1.0f - 2.0f / (__expf(2.0f * u) + 1.0f);
  return 0.5f * x * (1.0f + t);
}

// stage one 8 KB weight slice (one kt of one matmul) -> LDS slot
DEVINL void stage8(const unsigned short* __restrict__ wf_all,
                   unsigned short* slot, int slice, int tid) {
  const unsigned short* src = wf_all + (size_t)slice * 4096;
  const int wv = tid >> 6, l = tid & 63;
#pragma unroll
  for (int r = 0; r < 2; ++r) {
    int off = (r * 4 + wv) * 512;   // ush; wave-uniform base, HW adds lane*16B
    __builtin_amdgcn_global_load_lds(
        (const __attribute__((address_space(1))) unsigned int*)(src + off + l * 8),
        (__attribute__((address_space(3))) unsigned int*)(slot + off), 16, 0, 0);
  }
}

// ---------------------------------------------------------------------------
// Kernel 0: repack six 128x128 fp32 weights into bf16 MFMA *A*-fragment order
// (A = W^T, flipped). slice j = mat*4+kt; elem (j, mt, l, i) holds
// W[kt*32+(l>>4)*8+i][mt*16+(l&15)]  (Wa_q pre-scaled by QKS).
// ---------------------------------------------------------------------------
__global__ void prep_weights(const float* __restrict__ w0, const float* __restrict__ w1,
                             const float* __restrict__ w2, const float* __restrict__ w3,
                             const float* __restrict__ w4, const float* __restrict__ w5,
                             unsigned short* __restrict__ wfrag) {
  int gid = blockIdx.x * 256 + threadIdx.x;   // < 98304
  int i  = gid & 7;
  int l  = (gid >> 3) & 63;
  int mt = (gid >> 9) & 7;
  int kt = (gid >> 12) & 3;
  int mat = gid >> 14;
  const float* W = (mat == 0) ? w0 : (mat == 1) ? w1 : (mat == 2) ? w2
                 : (mat == 3) ? w3 : (mat == 4) ? w4 : w5;
  int k = kt * 32 + (l >> 4) * 8 + i;
  int c = mt * 16 + (l & 15);
  float v = W[k * 128 + c];
  if (mat == 1) v *= QKS;
  wfrag[gid] = f2bf(v);
}

// ---------------------------------------------------------------------------
// Kernel 1: kv = LN(x_kv) @ Wkv + bkv -> bf16 workspace [24576][256]  (R5)
// ---------------------------------------------------------------------------
__global__ __launch_bounds__(256) void kv_proj(
    const float* __restrict__ xkv, const float* __restrict__ lns,
    const float* __restrict__ lnb, const float* __restrict__ Wkv,
    const float* __restrict__ bkv, unsigned short* __restrict__ kvout) {
  __shared__ float y[16][132];
  const int tid = threadIdx.x;
  const size_t rb = (size_t)blockIdx.x * 16;
  {
    int r = tid >> 4, p = tid & 15;
    const float* xr = xkv + (rb + r) * 128 + p * 8;
    float v[8];
    float sum = 0.f, sq = 0.f;
#pragma unroll
    for (int i = 0; i < 2; ++i) {
      float4 q4 = *(const float4*)(xr + i * 4);
      v[i*4+0]=q4.x; v[i*4+1]=q4.y; v[i*4+2]=q4.z; v[i*4+3]=q4.w;
      sum += q4.x + q4.y + q4.z + q4.w;
      sq  += q4.x*q4.x + q4.y*q4.y + q4.z*q4.z + q4.w*q4.w;
    }
    sum += __shfl_xor(sum, 1, 16); sum += __shfl_xor(sum, 2, 16);
    sum += __shfl_xor(sum, 4, 16); sum += __shfl_xor(sum, 8, 16);
    sq  += __shfl_xor(sq, 1, 16);  sq  += __shfl_xor(sq, 2, 16);
    sq  += __shfl_xor(sq, 4, 16);  sq  += __shfl_xor(sq, 8, 16);
    float mu = sum * (1.0f/128.f);
    float rs = rsqrtf(sq * (1.0f/128.f) - mu*mu + 1e-5f);
#pragma unroll
    for (int i = 0; i < 8; ++i) {
      int c = p * 8 + i;
      y[r][c] = (v[i] - mu) * rs * lns[c] + lnb[c];
    }
  }
  __syncthreads();
  const int c2 = tid;
  float acc[16];
#pragma unroll
  for (int r = 0; r < 16; ++r) acc[r] = 0.f;
  for (int c = 0; c < 128; c += 4) {
    float w0 = Wkv[(c+0)*256 + c2];
    float w1 = Wkv[(c+1)*256 + c2];
    float w2 = Wkv[(c+2)*256 + c2];
    float w3 = Wkv[(c+3)*256 + c2];
#pragma unroll
    for (int r = 0; r < 16; ++r) {
      float4 yv = *(const float4*)&y[r][c];
      acc[r] += yv.x*w0 + yv.y*w1 + yv.z*w2 + yv.w*w3;
    }
  }
  float bb = bkv[c2];
#pragma unroll
  for (int r = 0; r < 16; ++r)
    kvout[(rb + r) * 256 + c2] = f2bf(acc[r] + bb);
}

// ---------------------------------------------------------------------------
// mmFlip: per-wave flipped 16x128 @ 128x128, A = W^T (LDS slice ping-pong,
// 8 KB/slice, stage j+1 at phase-j start, 1 barrier/phase), B = activation.
// Lane (lo,g) outputs out[q=lo][c = mt*16 + g*4 .. +3].
// MODE 0: (+bias) -> X (b64 writes). MODE 1: +bias, gelu -> X.
// MODE 2: x2 = xq + gamma*(acc+bias) -> packed bf16 regs x2p[16].
// MODE 3: m = acc+bias; out = unpack(x2p) + gmlp*m -> global float4.
// ---------------------------------------------------------------------------
template <int MODE>
DEVINL void mmFlip(unsigned short* X, unsigned short (*Wb)[4096],
                   const unsigned short* __restrict__ wf_all, int j0,
                   const float* __restrict__ bias,
                   const float* __restrict__ xqw, const float* __restrict__ gamma,
                   unsigned* x2p, const float* __restrict__ gmlp,
                   float* __restrict__ outw, int tid) {
  const int l = tid & 63, lo = l & 15, g = l >> 4;
  f32x4 acc[8];
#pragma unroll
  for (int mt = 0; mt < 8; ++mt) acc[mt] = f32x4_zero();

#pragma unroll
  for (int kt = 0; kt < 4; ++kt) {
    const int j = j0 + kt;
    if (j + 1 < 24) stage8(wf_all, Wb[(j + 1) & 1], j + 1, tid);
    const unsigned short* W = Wb[j & 1];
    bf16x8 b = *(const bf16x8*)(X + swz(lo, kt * 32 + g * 8));
#pragma unroll
    for (int mt = 0; mt < 8; ++mt) {
      bf16x8 a = *(const bf16x8*)(W + (mt * 64 + l) * 8);
      acc[mt] = mfma16(a, b, acc[mt]);
    }
    __syncthreads();   // all waves done with slice j; slice j+1 drained
  }

#pragma unroll
  for (int mt = 0; mt < 8; ++mt) {
    int c0 = mt * 16 + g * 4;
    float v0 = acc[mt][0], v1 = acc[mt][1], v2 = acc[mt][2], v3 = acc[mt][3];
    if (bias) {
      float4 b4 = *(const float4*)(bias + c0);
      v0 += b4.x; v1 += b4.y; v2 += b4.z; v3 += b4.w;
    }
    if (MODE == 1) { v0 = gelu_f(v0); v1 = gelu_f(v1); v2 = gelu_f(v2); v3 = gelu_f(v3); }
    if (MODE == 2) {
      float4 x4 = *(const float4*)(xqw + lo * 128 + c0);
      float4 g4 = *(const float4*)(gamma + c0);
      v0 = x4.x + g4.x * v0; v1 = x4.y + g4.y * v1;
      v2 = x4.z + g4.z * v2; v3 = x4.w + g4.w * v3;
      x2p[2 * mt]     = cvt_pk_bf16(v0, v1);
      x2p[2 * mt + 1] = cvt_pk_bf16(v2, v3);
    } else if (MODE == 3) {
      float4 p4 = *(const float4*)(gmlp + c0);
      unsigned xa = x2p[2 * mt], xb = x2p[2 * mt + 1];
      float4 o;
      o.x = bf2f((unsigned short)(xa & 0xffff))  + p4.x * v0;
      o.y = bf2f((unsigned short)(xa >> 16))     + p4.y * v1;
      o.z = bf2f((unsigned short)(xb & 0xffff))  + p4.z * v2;
      o.w = bf2f((unsigned short)(xb >> 16))     + p4.w * v3;
      *(float4*)(outw + lo * 128 + c0) = o;
    } else {
      uint2 w2;
      w2.x = cvt_pk_bf16(v0, v1);
      w2.y = cvt_pk_bf16(v2, v3);
      *(uint2*)(X + swz(lo, c0)) = w2;
    }
  }
}

// ---------------------------------------------------------------------------
// Kernel 2: fused main. Block = 4 waves x 1 s-unit each; 8 KB weight slices
// double-buffered (16 KB); per-wave LDS 6.25 KB (X 4KB + K 2.25KB); x2 in
// 16 packed-bf16 registers; V^T overlays X during PV. 41 KB -> 3 blocks/CU.
// ---------------------------------------------------------------------------
__global__ __launch_bounds__(256, 3) void fused_main(
    const float* __restrict__ xq, const int* __restrict__ nh_idx,
    const unsigned char* __restrict__ nh_mask,
    const unsigned short* __restrict__ wfrag,
    const unsigned short* __restrict__ kvws,
    const float* __restrict__ ln_q_s, const float* __restrict__ ln_q_b,
    const float* __restrict__ bq, const float* __restrict__ b_out,
    const float* __restrict__ gamma, const float* __restrict__ ln_m_s,
    const float* __restrict__ ln_m_b, const float* __restrict__ bm,
    const float* __restrict__ b1, const float* __restrict__ b2,
    const float* __restrict__ gmlp, float* __restrict__ out) {
  __shared__ __align__(16) unsigned short Wb[2][4096];   // 16 KB slice ping-pong
  __shared__ __align__(16) unsigned short SU[4][3200];   // X 2048 | K 1152 (ush)

  const int tid = threadIdx.x, l = tid & 63, wv = tid >> 6;
  const int lo = l & 15, g = l >> 4;
  const int su = blockIdx.x * 4 + wv;     // < 24576
  const int t = su / SS, s = su - t * SS;
  const float* xqw = xq + (size_t)su * 2048;
  float* outw = out + (size_t)su * 2048;
  unsigned short* X = SU[wv];             // activations [16 q][128 c] swz / V^T overlay
  unsigned short* K = SU[wv] + 2048;      // K rows [9][128] swz / P unused (P in regs)

  // ---- P0: stage slice 0; score bias; kv gather (K lands now, V held in regs)
  stage8(wfrag, Wb[0], 0, tid);
  float sbias[4];
#pragma unroll
  for (int e = 0; e < 4; ++e) {
    int n = g * 4 + e;
    sbias[e] = (n < 9) ? (nh_mask[s * 9 + n] ? 0.0f : -1e9f) : -1e9f;
  }
  uint4 gr[5];
  {
#pragma unroll
    for (int i = 0; i < 5; ++i) {
      int idx = i * 64 + l;               // 288 = 9 rows x 32 chunks of 16 B
      if (idx < 288) {
        int n = idx >> 5, ch = idx & 31;
        int jrow = nh_idx[s * 9 + n];
        gr[i] = *(const uint4*)(kvws + ((size_t)(t * SS + jrow)) * 256 + ch * 8);
      }
    }
#pragma unroll
    for (int i = 0; i < 5; ++i) {         // land K half immediately
      int idx = i * 64 + l;
      if (idx < 288 && (idx & 31) < 16) {
        int n = idx >> 5, ch = idx & 31;
        *(uint4*)(K + n * 128 + ((ch ^ (n & 7)) << 3)) = gr[i];
      }
    }
  }

  // ---- P1: LN1 -> X (flip layout: lane owns row lo, channels mt*16+g*4..+3)
  {
    float4 xv[8];
    float sum = 0.f, sq = 0.f;
#pragma unroll
    for (int mt = 0; mt < 8; ++mt) {
      xv[mt] = *(const float4*)(xqw + lo * 128 + mt * 16 + g * 4);
      sum += xv[mt].x + xv[mt].y + xv[mt].z + xv[mt].w;
      sq  += xv[mt].x*xv[mt].x + xv[mt].y*xv[mt].y + xv[mt].z*xv[mt].z + xv[mt].w*xv[mt].w;
    }
    sum += __shfl_xor(sum, 16); sum += __shfl_xor(sum, 32);
    sq  += __shfl_xor(sq, 16);  sq  += __shfl_xor(sq, 32);
    float mu = sum * (1.0f/128.f);
    float rs = rsqrtf(sq * (1.0f/128.f) - mu*mu + 1e-5f);
#pragma unroll
    for (int mt = 0; mt < 8; ++mt) {
      int c0 = mt * 16 + g * 4;
      float4 s4 = *(const float4*)(ln_q_s + c0);
      float4 b4 = *(const float4*)(ln_q_b + c0);
      uint2 w2;
      w2.x = cvt_pk_bf16((xv[mt].x - mu) * rs * s4.x + b4.x,
                         (xv[mt].y - mu) * rs * s4.y + b4.y);
      w2.y = cvt_pk_bf16((xv[mt].z - mu) * rs * s4.z + b4.z,
                         (xv[mt].w - mu) * rs * s4.w + b4.w);
      *(uint2*)(X + swz(lo, c0)) = w2;
    }
  }
  wave_sync();
  __syncthreads();   // slice 0 staged + everyone ready

  unsigned x2p[16];

  // q  = y1 @ Wq + bq            slices 0..3
  mmFlip<0>(X, Wb, wfrag, 0, bq, nullptr, nullptr, nullptr, nullptr, nullptr, tid);
  wave_sync();
  // qh = q @ (Wa_q * QKS)        slices 4..7
  mmFlip<0>(X, Wb, wfrag, 4, nullptr, nullptr, nullptr, nullptr, nullptr, nullptr, tid);
  wave_sync();

  // ---- attention (wave-local, MFMA; R5-proven layout)
  {
    const int krow = (lo > 8) ? 8 : lo;   // clamp; garbage rows killed by sbias
    f32x4 st[4];
#pragma unroll
    for (int h = 0; h < 4; ++h) {
      bf16x8 ka = *(const bf16x8*)(K + swz(krow, h * 32 + g * 8));  // A = K
      bf16x8 qb = *(const bf16x8*)(X + swz(lo,   h * 32 + g * 8));  // B = qh
      st[h] = mfma16(ka, qb, f32x4_zero());                         // St[n][q]
    }
    wave_sync();   // qh reads retired -> X reusable for V^T
    // land V^T into X: [8 nt][8 npair][16 d][2] (stale slots = finite qh)
#pragma unroll
    for (int i = 0; i < 5; ++i) {
      int idx = i * 64 + l;
      if (idx < 288 && (idx & 31) >= 16) {
        int n = idx >> 5, d0 = ((idx & 31) - 16) * 8;
        int nt = d0 >> 4;
        int base = nt * 256 + (n >> 1) * 32 + (d0 & 15) * 2 + (n & 1);
        const unsigned short* u = (const unsigned short*)&gr[i];
#pragma unroll
        for (int dd = 0; dd < 8; ++dd) X[base + dd * 2] = u[dd];
      }
    }
    // softmax over n (in-lane e + shfl over g) and P A-frag assembly
    bf16x8 pfrag[4];
#pragma unroll
    for (int h = 0; h < 4; ++h) {
      float p0 = st[h][0] + sbias[0], p1 = st[h][1] + sbias[1];
      float p2 = st[h][2] + sbias[2], p3 = st[h][3] + sbias[3];
      float m = fmaxf(fmaxf(p0, p1), fmaxf(p2, p3));
      m = fmaxf(m, __shfl_xor(m, 16)); m = fmaxf(m, __shfl_xor(m, 32));
      p0 = __expf(p0 - m); p1 = __expf(p1 - m);
      p2 = __expf(p2 - m); p3 = __expf(p3 - m);
      float ss = p0 + p1 + p2 + p3;
      ss += __shfl_xor(ss, 16); ss += __shfl_xor(ss, 32);
      float inv = 1.0f / ss;
      p0 *= inv; p1 *= inv; p2 *= inv; p3 *= inv;
      // lane needs P[q=lo][n=g*8+i]; own lane holds P[n=g*4+e][q=lo]
      float b0 = __shfl_xor(p0, 16), b1 = __shfl_xor(p1, 16),
            b2_ = __shfl_xor(p2, 16), b3 = __shfl_xor(p3, 16);
      float c0_ = __shfl_xor(p0, 32), c1 = __shfl_xor(p1, 32),
            c2 = __shfl_xor(p2, 32), c3 = __shfl_xor(p3, 32);
      float d0_ = __shfl_xor(p0, 48), d1 = __shfl_xor(p1, 48),
            d2 = __shfl_xor(p2, 48), d3 = __shfl_xor(p3, 48);
      float L0 = (g == 0) ? p0 : (g == 1) ? d0_ : 0.f;
      float L1 = (g == 0) ? p1 : (g == 1) ? d1 : 0.f;
      float L2 = (g == 0) ? p2 : (g == 1) ? d2 : 0.f;
      float L3 = (g == 0) ? p3 : (g == 1) ? d3 : 0.f;
      float H0 = (g == 0) ? b0 : (g == 1) ? c0_ : 0.f;
      float H1 = (g == 0) ? b1 : (g == 1) ? c1 : 0.f;
      float H2 = (g == 0) ? b2_ : (g == 1) ? c2 : 0.f;
      float H3 = (g == 0) ? b3 : (g == 1) ? c3 : 0.f;
      uint4 pu;
      pu.x = cvt_pk_bf16(L0, L1); pu.y = cvt_pk_bf16(L2, L3);
      pu.z = cvt_pk_bf16(H0, H1); pu.w = cvt_pk_bf16(H2, H3);
      pfrag[h] = __builtin_bit_cast(bf16x8, pu);
    }
    wave_sync();   // V^T writes landed
    // PV: out[q][d] = P @ V; B-frag = 4x ds_read_b32 (g<2 hold n=0..15)
    f32x4 oacc[8];
#pragma unroll
    for (int nt = 0; nt < 8; ++nt) {
      unsigned vw0 = 0, vw1 = 0, vw2 = 0, vw3 = 0;
      if (g < 2) {
        const unsigned short* vb = X + nt * 256 + g * 128 + lo * 2;
        vw0 = *(const unsigned*)(vb);
        vw1 = *(const unsigned*)(vb + 32);
        vw2 = *(const unsigned*)(vb + 64);
        vw3 = *(const unsigned*)(vb + 96);
      }
      uint4 vu; vu.x = vw0; vu.y = vw1; vu.z = vw2; vu.w = vw3;
      bf16x8 vfrag = __builtin_bit_cast(bf16x8, vu);
      oacc[nt] = mfma16(pfrag[nt >> 1], vfrag, f32x4_zero());
    }
    wave_sync();   // V^T reads done -> overwrite X with ao (full coverage)
#pragma unroll
    for (int nt = 0; nt < 8; ++nt)
#pragma unroll
      for (int e = 0; e < 4; ++e)
        X[swz(g * 4 + e, nt * 16 + lo)] = (unsigned short)(cvt_pk_bf16(oacc[nt][e], 0.f) & 0xffff);
    wave_sync();
  }

  // x2 = xq + gamma*(ao @ W_out + b_out) -> x2p regs   slices 8..11
  mmFlip<2>(X, Wb, wfrag, 8, b_out, xqw, gamma, x2p, nullptr, nullptr, tid);

  // ---- LN2 from x2p -> y2 -> X (lane owns full row lo)
  {
    float sum = 0.f, sq = 0.f;
    float xv[4];
#pragma unroll
    for (int mt = 0; mt < 8; ++mt) {
      unsigned xa = x2p[2*mt], xb = x2p[2*mt+1];
      xv[0] = bf2f((unsigned short)(xa & 0xffff));
      xv[1] = bf2f((unsigned short)(xa >> 16));
      xv[2] = bf2f((unsigned short)(xb & 0xffff));
      xv[3] = bf2f((unsigned short)(xb >> 16));
      sum += xv[0] + xv[1] + xv[2] + xv[3];
      sq  += xv[0]*xv[0] + xv[1]*xv[1] + xv[2]*xv[2] + xv[3]*xv[3];
    }
    sum += __shfl_xor(sum, 16); sum += __shfl_xor(sum, 32);
    sq  += __shfl_xor(sq, 16);  sq  += __shfl_xor(sq, 32);
    float mu = sum * (1.0f/128.f);
    float rs = rsqrtf(sq * (1.0f/128.f) - mu*mu + 1e-5f);
#pragma unroll
    for (int mt = 0; mt < 8; ++mt) {
      int c0 = mt * 16 + g * 4;
      unsigned xa = x2p[2*mt], xb = x2p[2*mt+1];
      float4 s4 = *(const float4*)(ln_m_s + c0);
      float4 b4 = *(const float4*)(ln_m_b + c0);
      uint2 w2;
      w2.x = cvt_pk_bf16((bf2f((unsigned short)(xa & 0xffff)) - mu) * rs * s4.x + b4.x,
                         (bf2f((unsigned short)(xa >> 16))    - mu) * rs * s4.y + b4.y);
      w2.y = cvt_pk_bf16((bf2f((unsigned short)(xb & 0xffff)) - mu) * rs * s4.z + b4.z,
                         (bf2f((unsigned short)(xb >> 16))    - mu) * rs * s4.w + b4.w);
      *(uint2*)(X + swz(lo, c0)) = w2;
    }
  }
  wave_sync();

  // h1 = y2 @ Wm + bm            slices 12..15
  mmFlip<0>(X, Wb, wfrag, 12, bm, nullptr, nullptr, nullptr, nullptr, nullptr, tid);
  wave_sync();
  // g1 = gelu(h1 @ W1 + b1)      slices 16..19
  mmFlip<1>(X, Wb, wfrag, 16, b1, nullptr, nullptr, nullptr, nullptr, nullptr, tid);
  wave_sync();
  // m = g1 @ W2 + b2; out = x2 + gmlp*m   slices 20..23
  mmFlip<3>(X, Wb, wfrag, 20, b2, nullptr, nullptr, x2p, gmlp, outw, tid);
}

// ---------------------------------------------------------------------------
extern "C" void kernel_launch(void* const* d_in, const int* in_sizes, int n_in,
                              void* d_out, int out_size, void* d_ws, size_t ws_size,
                              hipStream_t stream) {
  const float* x_q     = (const float*)d_in[0];
  const float* x_kv    = (const float*)d_in[1];
  const int* nh_idx    = (const int*)d_in[2];
  const unsigned char* nh_mask = (const unsigned char*)d_in[3];
  const float* ln_q_s  = (const float*)d_in[4];
  const float* ln_q_b  = (const float*)d_in[5];
  const float* Wq      = (const float*)d_in[6];
  const float* bq      = (const float*)d_in[7];
  const float* ln_kv_s = (const float*)d_in[8];
  const float* ln_kv_b = (const float*)d_in[9];
  const float* Wkv     = (const float*)d_in[10];
  const float* bkv     = (const float*)d_in[11];
  const float* Wa_q    = (const float*)d_in[12];
  const float* W_out   = (const float*)d_in[13];
  const float* b_out   = (const float*)d_in[14];
  const float* gamma   = (const float*)d_in[15];
  const float* ln_m_s  = (const float*)d_in[16];
  const float* ln_m_b  = (const float*)d_in[17];
  const float* Wm      = (const float*)d_in[18];
  const float* bm      = (const float*)d_in[19];
  const float* W1      = (const float*)d_in[20];
  const float* b1      = (const float*)d_in[21];
  const float* W2      = (const float*)d_in[22];
  const float* b2      = (const float*)d_in[23];
  const float* gmlp    = (const float*)d_in[24];

  unsigned short* wfrag = (unsigned short*)d_ws;          // 192 KB bf16 A-frags
  unsigned short* kvws  = wfrag + 6 * 16384;              // 12.6 MB bf16 kv

  prep_weights<<<384, 256, 0, stream>>>(Wq, Wa_q, W_out, Wm, W1, W2, wfrag);
  kv_proj<<<1536, 256, 0, stream>>>(x_kv, ln_kv_s, ln_kv_b, Wkv, bkv, kvws);
  fused_main<<<6144, 256, 0, stream>>>(
      x_q, nh_idx, nh_mask, wfrag, kvws, ln_q_s, ln_q_b, bq, b_out, gamma,
      ln_m_s, ln_m_b, bm, b1, b2, gmlp, (float*)d_out);
}